// Round 5
// baseline (268.488 us; speedup 1.0000x reference)
//
#include <hip/hip_runtime.h>

#define N_NODES 50000
#define N_EDGES 600000
#define IN_DIM  256
#define HID     128
#define BN_EPS  1e-5f

#define SCAN_BLOCKS ((N_NODES + 255) / 256)     // 196
#define HIST_BLOCKS ((N_EDGES + 255) / 256)     // 2344
#define PREPW_BLOCKS ((IN_DIM * HID) / 256)     // 128

typedef __attribute__((ext_vector_type(8))) short bf16x8;   // 8 bf16 = 4 VGPRs
typedef __attribute__((ext_vector_type(4))) float f32x4;

__device__ __forceinline__ ushort f2bf(float f) {           // RNE fp32->bf16
    union { float f; uint u; } v; v.f = f;
    return (ushort)((v.u + 0x7FFFu + ((v.u >> 16) & 1u)) >> 16);
}
__device__ __forceinline__ float bflo(uint u) {             // low bf16 of pair -> f32
    union { uint u; float f; } v; v.u = u << 16; return v.f;
}
__device__ __forceinline__ float bfhi(uint u) {             // high bf16 of pair -> f32
    union { uint u; float f; } v; v.u = u & 0xFFFF0000u; return v.f;
}

// ---------------------------------------------------------------------------
// zero: cnt = 0, colsum/colsumsq (256 floats) = 0
// ---------------------------------------------------------------------------
__global__ __launch_bounds__(256) void zero_kernel(int* cnt, float* colstats, int n) {
    int i = blockIdx.x * 256 + threadIdx.x;
    if (i < n) cnt[i] = 0;
    if (i < 256) colstats[i] = 0.0f;
}

// in-degree histogram on targets; trailing blocks convert W -> Wt (bf16, transposed)
__global__ __launch_bounds__(256) void hist_prepw_kernel(const int* __restrict__ col, int* cnt,
                                                         const float* __restrict__ W, ushort* Wt) {
    int b = blockIdx.x;
    if (b < HIST_BLOCKS) {
        int i = b * 256 + threadIdx.x;
        if (i < N_EDGES) atomicAdd(&cnt[col[i]], 1);
    } else {
        int i = (b - HIST_BLOCKS) * 256 + threadIdx.x;  // 0 .. 32767
        int n = i >> 8, k = i & 255;
        Wt[n * IN_DIM + k] = f2bf(W[(size_t)k * HID + n]);
    }
}

// ---------------------------------------------------------------------------
// 2-step exclusive scan of cnt[50000]: blocksums, then final (each block
// scans the 196 blocksums in LDS itself). Also dis = rsqrt(cnt+1).
// ---------------------------------------------------------------------------
__global__ __launch_bounds__(256) void scan_blocksum_kernel(const int* __restrict__ cnt,
                                                            int* blocksums, int n) {
    __shared__ int s[256];
    int i = blockIdx.x * 256 + threadIdx.x;
    s[threadIdx.x] = (i < n) ? cnt[i] : 0;
    __syncthreads();
    for (int off = 128; off > 0; off >>= 1) {
        if (threadIdx.x < off) s[threadIdx.x] += s[threadIdx.x + off];
        __syncthreads();
    }
    if (threadIdx.x == 0) blocksums[blockIdx.x] = s[0];
}

__global__ __launch_bounds__(256) void scan_final_kernel(const int* __restrict__ cnt,
                                                         const int* __restrict__ blocksums,
                                                         int* rowptr, int* cursor,
                                                         float* dis, int n) {
    __shared__ int s[256];
    __shared__ int bs[256];
    int t = threadIdx.x;
    int i = blockIdx.x * 256 + t;

    // scan the per-block sums (inclusive) in LDS
    bs[t] = (t < SCAN_BLOCKS) ? blocksums[t] : 0;
    __syncthreads();
    for (int off = 1; off < 256; off <<= 1) {
        int x = 0;
        if (t >= off) x = bs[t - off];
        __syncthreads();
        if (t >= off) bs[t] += x;
        __syncthreads();
    }
    int blockoff = (blockIdx.x == 0) ? 0 : bs[blockIdx.x - 1];

    // local inclusive scan of this block's counts
    int v = (i < n) ? cnt[i] : 0;
    s[t] = v;
    __syncthreads();
    for (int off = 1; off < 256; off <<= 1) {
        int x = 0;
        if (t >= off) x = s[t - off];
        __syncthreads();
        if (t >= off) s[t] += x;
        __syncthreads();
    }
    if (i < n) {
        int excl = blockoff + s[t] - v;
        rowptr[i] = excl;
        cursor[i] = excl;
        dis[i] = rsqrtf((float)v + 1.0f);   // +1 = self loop
    }
    if (i == n - 1) rowptr[n] = N_EDGES;
}

// scatter edges into CSR order: srcs[cursor[col]++] = row
__global__ __launch_bounds__(256) void fill_kernel(const int* __restrict__ row,
                                                   const int* __restrict__ col,
                                                   int* cursor, int* srcs, int E) {
    int i = blockIdx.x * 256 + threadIdx.x;
    if (i < E) {
        int c = col[i];
        int pos = atomicAdd(&cursor[c], 1);
        srcs[pos] = row[i];
    }
}

// ---------------------------------------------------------------------------
// GEMM via MFMA: h[M,128](bf16) = x[M,256] @ W[256,128].
// bf16 inputs (converted in staging), fp32 accumulate, bf16 h.
// ---------------------------------------------------------------------------
#define LDA 40

__global__ __launch_bounds__(256) void gemm_kernel(const float* __restrict__ x,
                                                   const ushort* __restrict__ Wt,
                                                   ushort* __restrict__ h2, int M) {
    __shared__ ushort As[64][LDA];
    __shared__ ushort Bs[128][LDA];
    const int t = threadIdx.x;
    const int row0 = blockIdx.x * 64;
    const int wave = t >> 6, lane = t & 63;
    const int lrow = lane & 15, quad = lane >> 4;

    f32x4 acc[8];
    #pragma unroll
    for (int c = 0; c < 8; c++) acc[c] = (f32x4){0.f, 0.f, 0.f, 0.f};

    const int arow = t >> 2, aq = t & 3;
    const int bn = t >> 1, bh = t & 1;

    for (int k0 = 0; k0 < IN_DIM; k0 += 32) {
        {
            int gr = row0 + arow;
            uint4 pk = make_uint4(0, 0, 0, 0);
            if (gr < M) {
                const float* src = x + (size_t)gr * IN_DIM + k0 + aq * 8;
                float4 f0 = *(const float4*)src;
                float4 f1 = *(const float4*)(src + 4);
                pk.x = f2bf(f0.x) | ((uint)f2bf(f0.y) << 16);
                pk.y = f2bf(f0.z) | ((uint)f2bf(f0.w) << 16);
                pk.z = f2bf(f1.x) | ((uint)f2bf(f1.y) << 16);
                pk.w = f2bf(f1.z) | ((uint)f2bf(f1.w) << 16);
            }
            *(uint4*)&As[arow][aq * 8] = pk;
        }
        {
            const uint4* src = (const uint4*)(Wt + (size_t)bn * IN_DIM + k0 + bh * 16);
            *(uint4*)&Bs[bn][bh * 16]     = src[0];
            *(uint4*)&Bs[bn][bh * 16 + 8] = src[1];
        }
        __syncthreads();

        bf16x8 af = *(const bf16x8*)&As[wave * 16 + lrow][quad * 8];
        #pragma unroll
        for (int c = 0; c < 8; c++) {
            bf16x8 bfr = *(const bf16x8*)&Bs[c * 16 + lrow][quad * 8];
            acc[c] = __builtin_amdgcn_mfma_f32_16x16x32_bf16(af, bfr, acc[c], 0, 0, 0);
        }
        __syncthreads();
    }

    #pragma unroll
    for (int c = 0; c < 8; c++) {
        #pragma unroll
        for (int r = 0; r < 4; r++) {
            int gr = row0 + wave * 16 + quad * 4 + r;
            if (gr < M) h2[(size_t)gr * HID + c * 16 + lrow] = f2bf(acc[c][r]);
        }
    }
}

// ---------------------------------------------------------------------------
// Gather + fused column stats. ONE WAVE PER NODE (50000 waves), 16 waves/block,
// grid = 3125 (exact). h rows bf16: lane loads uint = 2 bf16.
// out[n] = dis[n]*(dis[n]*h[n] + sum dis[s]*h[s]); block-reduce stats.
// ---------------------------------------------------------------------------
#define GW 16   // waves per block; 50000 % 16 == 0 with grid 3125

__global__ __launch_bounds__(1024) void gather_kernel(const int* __restrict__ rowptr,
                                                      const int* __restrict__ srcs,
                                                      const float* __restrict__ dis,
                                                      const uint* __restrict__ h2,   // 64 uints/row
                                                      float* __restrict__ out,
                                                      float* colsum, float* colsumsq) {
    const int wave = threadIdx.x >> 6, lane = threadIdx.x & 63;
    const int node = blockIdx.x * GW + wave;        // always < N_NODES

    int beg = rowptr[node], end = rowptr[node + 1];
    float dn = dis[node];
    uint u = h2[(size_t)node * 64 + lane];
    float ax = bflo(u) * dn, ay = bfhi(u) * dn;     // self-loop (pre dn factor)

    int e = beg;
    for (; e + 4 <= end; e += 4) {                  // 4 independent gathers in flight
        int sa = srcs[e], sb = srcs[e + 1], sc = srcs[e + 2], sd = srcs[e + 3];
        uint ua = h2[(size_t)sa * 64 + lane];
        uint ub = h2[(size_t)sb * 64 + lane];
        uint uc = h2[(size_t)sc * 64 + lane];
        uint ud = h2[(size_t)sd * 64 + lane];
        float da = dis[sa], db = dis[sb], dc = dis[sc], dd = dis[sd];
        ax = fmaf(bflo(ua), da, ax); ay = fmaf(bfhi(ua), da, ay);
        ax = fmaf(bflo(ub), db, ax); ay = fmaf(bfhi(ub), db, ay);
        ax = fmaf(bflo(uc), dc, ax); ay = fmaf(bfhi(uc), dc, ay);
        ax = fmaf(bflo(ud), dd, ax); ay = fmaf(bfhi(ud), dd, ay);
    }
    for (; e < end; e++) {
        int s = srcs[e];
        uint uv = h2[(size_t)s * 64 + lane];
        float ds = dis[s];
        ax = fmaf(bflo(uv), ds, ax); ay = fmaf(bfhi(uv), ds, ay);
    }
    ax *= dn; ay *= dn;
    ((float2*)(out + (size_t)node * HID))[lane] = make_float2(ax, ay);

    // block stat reduction: 16 waves x 128 cols in LDS, then 256 atomics/block
    __shared__ float rs[GW][HID];
    __shared__ float rq[GW][HID];
    rs[wave][lane * 2]     = ax;
    rs[wave][lane * 2 + 1] = ay;
    rq[wave][lane * 2]     = ax * ax;
    rq[wave][lane * 2 + 1] = ay * ay;
    __syncthreads();
    int t = threadIdx.x;
    if (t < HID) {
        float s = 0.f, q = 0.f;
        #pragma unroll
        for (int w = 0; w < GW; w++) { s += rs[w][t]; q += rq[w][t]; }
        atomicAdd(&colsum[t], s);
        atomicAdd(&colsumsq[t], q);
    }
}

// ---------------------------------------------------------------------------
// BN (training stats, biased var) + ReLU, in place. (bias b cancels in BN)
// ---------------------------------------------------------------------------
__global__ __launch_bounds__(256) void bn_relu_kernel(float* __restrict__ out,
                                                      const float* __restrict__ colsum,
                                                      const float* __restrict__ colsumsq,
                                                      const float* __restrict__ gamma,
                                                      const float* __restrict__ beta, int M) {
    size_t i = (size_t)blockIdx.x * 256 + threadIdx.x;
    size_t total = (size_t)M * (HID / 4);
    if (i >= total) return;
    int c4 = (int)((i & (HID / 4 - 1)) * 4);
    float4 v = ((const float4*)out)[i];
    float vv[4] = {v.x, v.y, v.z, v.w};
    float res[4];
    const float invN = 1.0f / (float)M;
    #pragma unroll
    for (int j = 0; j < 4; j++) {
        int c = c4 + j;
        float mean = colsum[c] * invN;
        float var  = colsumsq[c] * invN - mean * mean;
        var = fmaxf(var, 0.0f);
        float sc = gamma[c] * rsqrtf(var + BN_EPS);
        res[j] = fmaxf(0.0f, (vv[j] - mean) * sc + beta[c]);
    }
    ((float4*)out)[i] = make_float4(res[0], res[1], res[2], res[3]);
}

// ---------------------------------------------------------------------------
extern "C" void kernel_launch(void* const* d_in, const int* in_sizes, int n_in,
                              void* d_out, int out_size, void* d_ws, size_t ws_size,
                              hipStream_t stream) {
    const float* x     = (const float*)d_in[0];
    const int*   ei    = (const int*)  d_in[1];   // [2,E] flat: row(src) then col(dst)
    const float* W     = (const float*)d_in[2];
    // d_in[3] = b: cancels inside BatchNorm -> unused
    const float* gamma = (const float*)d_in[4];
    const float* beta  = (const float*)d_in[5];
    float* out = (float*)d_out;

    const int* row = ei;
    const int* col = ei + N_EDGES;

    // workspace layout (4-byte words)
    int*    cnt       = (int*)d_ws;                        // [50000]
    float*  dis       = (float*)d_ws + 50000;              // [50000]
    int*    rowptr    = (int*)d_ws + 100000;               // [50001]
    int*    cursor    = (int*)d_ws + 150016;               // [50000]
    int*    blocksums = (int*)d_ws + 200016;               // [256]
    int*    srcs      = (int*)d_ws + 200272;               // [600000]
    ushort* Wt        = (ushort*)((int*)d_ws + 800272);    // [128*256] bf16 (16384 words)
    ushort* h2        = (ushort*)((int*)d_ws + 816656);    // [50000*128] bf16 (3.2M words)
    float*  colsum    = (float*)d_ws + 4016656;            // [128]
    float*  colsumsq  = (float*)d_ws + 4016784;            // [128]

    zero_kernel<<<(N_NODES + 255) / 256, 256, 0, stream>>>(cnt, colsum, N_NODES);

    hist_prepw_kernel<<<HIST_BLOCKS + PREPW_BLOCKS, 256, 0, stream>>>(col, cnt, W, Wt);

    scan_blocksum_kernel<<<SCAN_BLOCKS, 256, 0, stream>>>(cnt, blocksums, N_NODES);
    scan_final_kernel<<<SCAN_BLOCKS, 256, 0, stream>>>(cnt, blocksums, rowptr, cursor, dis, N_NODES);

    fill_kernel<<<HIST_BLOCKS, 256, 0, stream>>>(row, col, cursor, srcs, N_EDGES);

    gemm_kernel<<<(N_NODES + 63) / 64, 256, 0, stream>>>(x, Wt, h2, N_NODES);

    gather_kernel<<<N_NODES / GW, 1024, 0, stream>>>(rowptr, srcs, dis, (const uint*)h2, out,
                                                     colsum, colsumsq);

    {
        size_t total = (size_t)N_NODES * (HID / 4);
        bn_relu_kernel<<<(int)((total + 255) / 256), 256, 0, stream>>>(out, colsum, colsumsq, gamma, beta, N_NODES);
    }
}

// Round 6
// 264.297 us; speedup vs baseline: 1.0159x; 1.0159x over previous
//
#include <hip/hip_runtime.h>

#define N_NODES 50000
#define N_EDGES 600000
#define IN_DIM  256
#define HID     128
#define BN_EPS  1e-5f

#define SCAN_BLOCKS ((N_NODES + 255) / 256)     // 196
#define HIST_BLOCKS ((N_EDGES + 255) / 256)     // 2344
#define PREPW_BLOCKS ((IN_DIM * HID) / 256)     // 128

typedef __attribute__((ext_vector_type(8))) short bf16x8;   // 8 bf16 = 4 VGPRs
typedef __attribute__((ext_vector_type(4))) float f32x4;

__device__ __forceinline__ ushort f2bf(float f) {           // RNE fp32->bf16
    union { float f; uint u; } v; v.f = f;
    return (ushort)((v.u + 0x7FFFu + ((v.u >> 16) & 1u)) >> 16);
}
__device__ __forceinline__ float bflo(uint u) {             // low bf16 of pair -> f32
    union { uint u; float f; } v; v.u = u << 16; return v.f;
}
__device__ __forceinline__ float bfhi(uint u) {             // high bf16 of pair -> f32
    union { uint u; float f; } v; v.u = u & 0xFFFF0000u; return v.f;
}

// ---------------------------------------------------------------------------
// zero: cnt = 0, colsum/colsumsq (256 floats) = 0
// ---------------------------------------------------------------------------
__global__ __launch_bounds__(256) void zero_kernel(int* cnt, float* colstats, int n) {
    int i = blockIdx.x * 256 + threadIdx.x;
    if (i < n) cnt[i] = 0;
    if (i < 256) colstats[i] = 0.0f;
}

// in-degree histogram on targets; trailing blocks convert W -> Wt (bf16, transposed)
__global__ __launch_bounds__(256) void hist_prepw_kernel(const int* __restrict__ col, int* cnt,
                                                         const float* __restrict__ W, ushort* Wt) {
    int b = blockIdx.x;
    if (b < HIST_BLOCKS) {
        int i = b * 256 + threadIdx.x;
        if (i < N_EDGES) atomicAdd(&cnt[col[i]], 1);
    } else {
        int i = (b - HIST_BLOCKS) * 256 + threadIdx.x;  // 0 .. 32767
        int n = i >> 8, k = i & 255;
        Wt[n * IN_DIM + k] = f2bf(W[(size_t)k * HID + n]);
    }
}

// ---------------------------------------------------------------------------
// 2-step exclusive scan of cnt[50000]: blocksums, then final (each block
// scans the 196 blocksums in LDS itself). Also dis = rsqrt(cnt+1).
// ---------------------------------------------------------------------------
__global__ __launch_bounds__(256) void scan_blocksum_kernel(const int* __restrict__ cnt,
                                                            int* blocksums, int n) {
    __shared__ int s[256];
    int i = blockIdx.x * 256 + threadIdx.x;
    s[threadIdx.x] = (i < n) ? cnt[i] : 0;
    __syncthreads();
    for (int off = 128; off > 0; off >>= 1) {
        if (threadIdx.x < off) s[threadIdx.x] += s[threadIdx.x + off];
        __syncthreads();
    }
    if (threadIdx.x == 0) blocksums[blockIdx.x] = s[0];
}

__global__ __launch_bounds__(256) void scan_final_kernel(const int* __restrict__ cnt,
                                                         const int* __restrict__ blocksums,
                                                         int* rowptr, int* cursor,
                                                         float* dis, int n) {
    __shared__ int s[256];
    __shared__ int bs[256];
    int t = threadIdx.x;
    int i = blockIdx.x * 256 + t;

    // scan the per-block sums (inclusive) in LDS
    bs[t] = (t < SCAN_BLOCKS) ? blocksums[t] : 0;
    __syncthreads();
    for (int off = 1; off < 256; off <<= 1) {
        int x = 0;
        if (t >= off) x = bs[t - off];
        __syncthreads();
        if (t >= off) bs[t] += x;
        __syncthreads();
    }
    int blockoff = (blockIdx.x == 0) ? 0 : bs[blockIdx.x - 1];

    // local inclusive scan of this block's counts
    int v = (i < n) ? cnt[i] : 0;
    s[t] = v;
    __syncthreads();
    for (int off = 1; off < 256; off <<= 1) {
        int x = 0;
        if (t >= off) x = s[t - off];
        __syncthreads();
        if (t >= off) s[t] += x;
        __syncthreads();
    }
    if (i < n) {
        int excl = blockoff + s[t] - v;
        rowptr[i] = excl;
        cursor[i] = excl;
        dis[i] = rsqrtf((float)v + 1.0f);   // +1 = self loop
    }
    if (i == n - 1) rowptr[n] = N_EDGES;
}

// scatter edges into CSR order: srcs[cursor[col]++] = row
__global__ __launch_bounds__(256) void fill_kernel(const int* __restrict__ row,
                                                   const int* __restrict__ col,
                                                   int* cursor, int* srcs, int E) {
    int i = blockIdx.x * 256 + threadIdx.x;
    if (i < E) {
        int c = col[i];
        int pos = atomicAdd(&cursor[c], 1);
        srcs[pos] = row[i];
    }
}

// ---------------------------------------------------------------------------
// GEMM via MFMA: h[M,128](bf16) = x[M,256] @ W[256,128].
// bf16 inputs (converted in staging), fp32 accumulate, bf16 h.
// ---------------------------------------------------------------------------
#define LDA 40

__global__ __launch_bounds__(256) void gemm_kernel(const float* __restrict__ x,
                                                   const ushort* __restrict__ Wt,
                                                   ushort* __restrict__ h2, int M) {
    __shared__ ushort As[64][LDA];
    __shared__ ushort Bs[128][LDA];
    const int t = threadIdx.x;
    const int row0 = blockIdx.x * 64;
    const int wave = t >> 6, lane = t & 63;
    const int lrow = lane & 15, quad = lane >> 4;

    f32x4 acc[8];
    #pragma unroll
    for (int c = 0; c < 8; c++) acc[c] = (f32x4){0.f, 0.f, 0.f, 0.f};

    const int arow = t >> 2, aq = t & 3;
    const int bn = t >> 1, bh = t & 1;

    for (int k0 = 0; k0 < IN_DIM; k0 += 32) {
        {
            int gr = row0 + arow;
            uint4 pk = make_uint4(0, 0, 0, 0);
            if (gr < M) {
                const float* src = x + (size_t)gr * IN_DIM + k0 + aq * 8;
                float4 f0 = *(const float4*)src;
                float4 f1 = *(const float4*)(src + 4);
                pk.x = f2bf(f0.x) | ((uint)f2bf(f0.y) << 16);
                pk.y = f2bf(f0.z) | ((uint)f2bf(f0.w) << 16);
                pk.z = f2bf(f1.x) | ((uint)f2bf(f1.y) << 16);
                pk.w = f2bf(f1.z) | ((uint)f2bf(f1.w) << 16);
            }
            *(uint4*)&As[arow][aq * 8] = pk;
        }
        {
            const uint4* src = (const uint4*)(Wt + (size_t)bn * IN_DIM + k0 + bh * 16);
            *(uint4*)&Bs[bn][bh * 16]     = src[0];
            *(uint4*)&Bs[bn][bh * 16 + 8] = src[1];
        }
        __syncthreads();

        bf16x8 af = *(const bf16x8*)&As[wave * 16 + lrow][quad * 8];
        #pragma unroll
        for (int c = 0; c < 8; c++) {
            bf16x8 bfr = *(const bf16x8*)&Bs[c * 16 + lrow][quad * 8];
            acc[c] = __builtin_amdgcn_mfma_f32_16x16x32_bf16(af, bfr, acc[c], 0, 0, 0);
        }
        __syncthreads();
    }

    #pragma unroll
    for (int c = 0; c < 8; c++) {
        #pragma unroll
        for (int r = 0; r < 4; r++) {
            int gr = row0 + wave * 16 + quad * 4 + r;
            if (gr < M) h2[(size_t)gr * HID + c * 16 + lrow] = f2bf(acc[c][r]);
        }
    }
}

// ---------------------------------------------------------------------------
// Gather + fused column stats. 256-thr blocks (4 waves), grid 2048 = 8192
// waves (full residency); each wave grid-strides ~6 nodes (imbalance
// smoothing). One wave per node per iteration; 8 row-gathers in flight.
// out[n] = dis[n]*(dis[n]*h[n] + sum dis[s]*h[s]); block-reduce stats.
// ---------------------------------------------------------------------------
#define GATHER_BLOCKS 2048
#define GW 4

__global__ __launch_bounds__(256) void gather_kernel(const int* __restrict__ rowptr,
                                                     const int* __restrict__ srcs,
                                                     const float* __restrict__ dis,
                                                     const uint* __restrict__ h2,   // 64 uints/row
                                                     float* __restrict__ out,
                                                     float* colsum, float* colsumsq) {
    const int wave = threadIdx.x >> 6, lane = threadIdx.x & 63;
    float s0 = 0.f, s1 = 0.f, q0 = 0.f, q1 = 0.f;

    for (int node = blockIdx.x * GW + wave; node < N_NODES; node += GATHER_BLOCKS * GW) {
        int beg = rowptr[node], end = rowptr[node + 1];
        float dn = dis[node];
        uint u = h2[(size_t)node * 64 + lane];
        float ax = bflo(u) * dn, ay = bfhi(u) * dn;    // self-loop (pre dn factor)

        int e = beg;
        for (; e + 8 <= end; e += 8) {                 // 8 independent gathers in flight
            int si[8]; uint uu[8]; float dd[8];
            #pragma unroll
            for (int j = 0; j < 8; j++) si[j] = srcs[e + j];
            #pragma unroll
            for (int j = 0; j < 8; j++) uu[j] = h2[(size_t)si[j] * 64 + lane];
            #pragma unroll
            for (int j = 0; j < 8; j++) dd[j] = dis[si[j]];
            #pragma unroll
            for (int j = 0; j < 8; j++) {
                ax = fmaf(bflo(uu[j]), dd[j], ax);
                ay = fmaf(bfhi(uu[j]), dd[j], ay);
            }
        }
        for (; e + 4 <= end; e += 4) {
            int si[4]; uint uu[4]; float dd[4];
            #pragma unroll
            for (int j = 0; j < 4; j++) si[j] = srcs[e + j];
            #pragma unroll
            for (int j = 0; j < 4; j++) uu[j] = h2[(size_t)si[j] * 64 + lane];
            #pragma unroll
            for (int j = 0; j < 4; j++) dd[j] = dis[si[j]];
            #pragma unroll
            for (int j = 0; j < 4; j++) {
                ax = fmaf(bflo(uu[j]), dd[j], ax);
                ay = fmaf(bfhi(uu[j]), dd[j], ay);
            }
        }
        for (; e < end; e++) {
            int s = srcs[e];
            uint uv = h2[(size_t)s * 64 + lane];
            float ds = dis[s];
            ax = fmaf(bflo(uv), ds, ax); ay = fmaf(bfhi(uv), ds, ay);
        }
        ax *= dn; ay *= dn;
        ((float2*)(out + (size_t)node * HID))[lane] = make_float2(ax, ay);
        s0 += ax; s1 += ay;
        q0 = fmaf(ax, ax, q0); q1 = fmaf(ay, ay, q1);
    }

    // block stat reduction: 4 waves x 128 cols in LDS, then 256 atomics/block
    __shared__ float rs[GW][HID];
    __shared__ float rq[GW][HID];
    rs[wave][lane * 2]     = s0;
    rs[wave][lane * 2 + 1] = s1;
    rq[wave][lane * 2]     = q0;
    rq[wave][lane * 2 + 1] = q1;
    __syncthreads();
    int t = threadIdx.x;
    if (t < HID) {
        float s = rs[0][t] + rs[1][t] + rs[2][t] + rs[3][t];
        float q = rq[0][t] + rq[1][t] + rq[2][t] + rq[3][t];
        atomicAdd(&colsum[t], s);
        atomicAdd(&colsumsq[t], q);
    }
}

// ---------------------------------------------------------------------------
// BN (training stats, biased var) + ReLU, in place. (bias b cancels in BN)
// ---------------------------------------------------------------------------
__global__ __launch_bounds__(256) void bn_relu_kernel(float* __restrict__ out,
                                                      const float* __restrict__ colsum,
                                                      const float* __restrict__ colsumsq,
                                                      const float* __restrict__ gamma,
                                                      const float* __restrict__ beta, int M) {
    size_t i = (size_t)blockIdx.x * 256 + threadIdx.x;
    size_t total = (size_t)M * (HID / 4);
    if (i >= total) return;
    int c4 = (int)((i & (HID / 4 - 1)) * 4);
    float4 v = ((const float4*)out)[i];
    float vv[4] = {v.x, v.y, v.z, v.w};
    float res[4];
    const float invN = 1.0f / (float)M;
    #pragma unroll
    for (int j = 0; j < 4; j++) {
        int c = c4 + j;
        float mean = colsum[c] * invN;
        float var  = colsumsq[c] * invN - mean * mean;
        var = fmaxf(var, 0.0f);
        float sc = gamma[c] * rsqrtf(var + BN_EPS);
        res[j] = fmaxf(0.0f, (vv[j] - mean) * sc + beta[c]);
    }
    ((float4*)out)[i] = make_float4(res[0], res[1], res[2], res[3]);
}

// ---------------------------------------------------------------------------
extern "C" void kernel_launch(void* const* d_in, const int* in_sizes, int n_in,
                              void* d_out, int out_size, void* d_ws, size_t ws_size,
                              hipStream_t stream) {
    const float* x     = (const float*)d_in[0];
    const int*   ei    = (const int*)  d_in[1];   // [2,E] flat: row(src) then col(dst)
    const float* W     = (const float*)d_in[2];
    // d_in[3] = b: cancels inside BatchNorm -> unused
    const float* gamma = (const float*)d_in[4];
    const float* beta  = (const float*)d_in[5];
    float* out = (float*)d_out;

    const int* row = ei;
    const int* col = ei + N_EDGES;

    // workspace layout (4-byte words)
    int*    cnt       = (int*)d_ws;                        // [50000]
    float*  dis       = (float*)d_ws + 50000;              // [50000]
    int*    rowptr    = (int*)d_ws + 100000;               // [50001]
    int*    cursor    = (int*)d_ws + 150016;               // [50000]
    int*    blocksums = (int*)d_ws + 200016;               // [256]
    int*    srcs      = (int*)d_ws + 200272;               // [600000]
    ushort* Wt        = (ushort*)((int*)d_ws + 800272);    // [128*256] bf16 (16384 words)
    ushort* h2        = (ushort*)((int*)d_ws + 816656);    // [50000*128] bf16 (3.2M words)
    float*  colsum    = (float*)d_ws + 4016656;            // [128]
    float*  colsumsq  = (float*)d_ws + 4016784;            // [128]

    zero_kernel<<<(N_NODES + 255) / 256, 256, 0, stream>>>(cnt, colsum, N_NODES);

    hist_prepw_kernel<<<HIST_BLOCKS + PREPW_BLOCKS, 256, 0, stream>>>(col, cnt, W, Wt);

    scan_blocksum_kernel<<<SCAN_BLOCKS, 256, 0, stream>>>(cnt, blocksums, N_NODES);
    scan_final_kernel<<<SCAN_BLOCKS, 256, 0, stream>>>(cnt, blocksums, rowptr, cursor, dis, N_NODES);

    fill_kernel<<<HIST_BLOCKS, 256, 0, stream>>>(row, col, cursor, srcs, N_EDGES);

    gemm_kernel<<<(N_NODES + 63) / 64, 256, 0, stream>>>(x, Wt, h2, N_NODES);

    gather_kernel<<<GATHER_BLOCKS, 256, 0, stream>>>(rowptr, srcs, dis, (const uint*)h2, out,
                                                     colsum, colsumsq);

    {
        size_t total = (size_t)N_NODES * (HID / 4);
        bn_relu_kernel<<<(int)((total + 255) / 256), 256, 0, stream>>>(out, colsum, colsumsq, gamma, beta, N_NODES);
    }
}

// Round 7
// 258.633 us; speedup vs baseline: 1.0381x; 1.0219x over previous
//
#include <hip/hip_runtime.h>

#define N_NODES 50000
#define N_EDGES 600000
#define IN_DIM  256
#define HID     128
#define BN_EPS  1e-5f

#define SCAN_BLOCKS ((N_NODES + 255) / 256)     // 196
#define HIST_BLOCKS ((N_EDGES + 255) / 256)     // 2344
#define PREPW_BLOCKS ((IN_DIM * HID) / 256)     // 128

typedef __attribute__((ext_vector_type(8))) short bf16x8;   // 8 bf16 = 4 VGPRs
typedef __attribute__((ext_vector_type(4))) float f32x4;

__device__ __forceinline__ ushort f2bf(float f) {           // RNE fp32->bf16
    union { float f; uint u; } v; v.f = f;
    return (ushort)((v.u + 0x7FFFu + ((v.u >> 16) & 1u)) >> 16);
}
__device__ __forceinline__ float bflo(uint u) {             // low bf16 of pair -> f32
    union { uint u; float f; } v; v.u = u << 16; return v.f;
}
__device__ __forceinline__ float bfhi(uint u) {             // high bf16 of pair -> f32
    union { uint u; float f; } v; v.u = u & 0xFFFF0000u; return v.f;
}

// ---------------------------------------------------------------------------
// zero: cnt = 0, colsum/colsumsq (256 floats) = 0
// ---------------------------------------------------------------------------
__global__ __launch_bounds__(256) void zero_kernel(int* cnt, float* colstats, int n) {
    int i = blockIdx.x * 256 + threadIdx.x;
    if (i < n) cnt[i] = 0;
    if (i < 256) colstats[i] = 0.0f;
}

// in-degree histogram on targets; trailing blocks convert W -> Wt (bf16, transposed)
__global__ __launch_bounds__(256) void hist_prepw_kernel(const int* __restrict__ col, int* cnt,
                                                         const float* __restrict__ W, ushort* Wt) {
    int b = blockIdx.x;
    if (b < HIST_BLOCKS) {
        int i = b * 256 + threadIdx.x;
        if (i < N_EDGES) atomicAdd(&cnt[col[i]], 1);
    } else {
        int i = (b - HIST_BLOCKS) * 256 + threadIdx.x;  // 0 .. 32767
        int n = i >> 8, k = i & 255;
        Wt[n * IN_DIM + k] = f2bf(W[(size_t)k * HID + n]);
    }
}

// ---------------------------------------------------------------------------
// 2-step exclusive scan of cnt[50000]: blocksums, then final (each block
// scans the 196 blocksums in LDS itself). Also dis = rsqrt(cnt+1).
// ---------------------------------------------------------------------------
__global__ __launch_bounds__(256) void scan_blocksum_kernel(const int* __restrict__ cnt,
                                                            int* blocksums, int n) {
    __shared__ int s[256];
    int i = blockIdx.x * 256 + threadIdx.x;
    s[threadIdx.x] = (i < n) ? cnt[i] : 0;
    __syncthreads();
    for (int off = 128; off > 0; off >>= 1) {
        if (threadIdx.x < off) s[threadIdx.x] += s[threadIdx.x + off];
        __syncthreads();
    }
    if (threadIdx.x == 0) blocksums[blockIdx.x] = s[0];
}

__global__ __launch_bounds__(256) void scan_final_kernel(const int* __restrict__ cnt,
                                                         const int* __restrict__ blocksums,
                                                         int* rowptr, int* cursor,
                                                         float* dis, int n) {
    __shared__ int s[256];
    __shared__ int bs[256];
    int t = threadIdx.x;
    int i = blockIdx.x * 256 + t;

    bs[t] = (t < SCAN_BLOCKS) ? blocksums[t] : 0;
    __syncthreads();
    for (int off = 1; off < 256; off <<= 1) {
        int x = 0;
        if (t >= off) x = bs[t - off];
        __syncthreads();
        if (t >= off) bs[t] += x;
        __syncthreads();
    }
    int blockoff = (blockIdx.x == 0) ? 0 : bs[blockIdx.x - 1];

    int v = (i < n) ? cnt[i] : 0;
    s[t] = v;
    __syncthreads();
    for (int off = 1; off < 256; off <<= 1) {
        int x = 0;
        if (t >= off) x = s[t - off];
        __syncthreads();
        if (t >= off) s[t] += x;
        __syncthreads();
    }
    if (i < n) {
        int excl = blockoff + s[t] - v;
        rowptr[i] = excl;
        cursor[i] = excl;
        dis[i] = rsqrtf((float)v + 1.0f);   // +1 = self loop
    }
    if (i == n - 1) rowptr[n] = N_EDGES;
}

// scatter edges into CSR order: srcs[cursor[col]++] = row
__global__ __launch_bounds__(256) void fill_kernel(const int* __restrict__ row,
                                                   const int* __restrict__ col,
                                                   int* cursor, int* srcs, int E) {
    int i = blockIdx.x * 256 + threadIdx.x;
    if (i < E) {
        int c = col[i];
        int pos = atomicAdd(&cursor[c], 1);
        srcs[pos] = row[i];
    }
}

// ---------------------------------------------------------------------------
// GEMM via MFMA: h2[M,128](bf16) = (x[M,256] @ W[256,128]) * dis[row]
// (pre-scaling by dis[src] here removes the per-edge dis load in gather:
//  out[n] = dis[n] * (h2[n] + sum_{s in N(n)} h2[s]))
// ---------------------------------------------------------------------------
#define LDA 40

__global__ __launch_bounds__(256) void gemm_kernel(const float* __restrict__ x,
                                                   const ushort* __restrict__ Wt,
                                                   const float* __restrict__ dis,
                                                   ushort* __restrict__ h2, int M) {
    __shared__ ushort As[64][LDA];
    __shared__ ushort Bs[128][LDA];
    const int t = threadIdx.x;
    const int row0 = blockIdx.x * 64;
    const int wave = t >> 6, lane = t & 63;
    const int lrow = lane & 15, quad = lane >> 4;

    f32x4 acc[8];
    #pragma unroll
    for (int c = 0; c < 8; c++) acc[c] = (f32x4){0.f, 0.f, 0.f, 0.f};

    const int arow = t >> 2, aq = t & 3;
    const int bn = t >> 1, bh = t & 1;

    for (int k0 = 0; k0 < IN_DIM; k0 += 32) {
        {
            int gr = row0 + arow;
            uint4 pk = make_uint4(0, 0, 0, 0);
            if (gr < M) {
                const float* src = x + (size_t)gr * IN_DIM + k0 + aq * 8;
                float4 f0 = *(const float4*)src;
                float4 f1 = *(const float4*)(src + 4);
                pk.x = f2bf(f0.x) | ((uint)f2bf(f0.y) << 16);
                pk.y = f2bf(f0.z) | ((uint)f2bf(f0.w) << 16);
                pk.z = f2bf(f1.x) | ((uint)f2bf(f1.y) << 16);
                pk.w = f2bf(f1.z) | ((uint)f2bf(f1.w) << 16);
            }
            *(uint4*)&As[arow][aq * 8] = pk;
        }
        {
            const uint4* src = (const uint4*)(Wt + (size_t)bn * IN_DIM + k0 + bh * 16);
            *(uint4*)&Bs[bn][bh * 16]     = src[0];
            *(uint4*)&Bs[bn][bh * 16 + 8] = src[1];
        }
        __syncthreads();

        bf16x8 af = *(const bf16x8*)&As[wave * 16 + lrow][quad * 8];
        #pragma unroll
        for (int c = 0; c < 8; c++) {
            bf16x8 bfr = *(const bf16x8*)&Bs[c * 16 + lrow][quad * 8];
            acc[c] = __builtin_amdgcn_mfma_f32_16x16x32_bf16(af, bfr, acc[c], 0, 0, 0);
        }
        __syncthreads();
    }

    // epilogue: C/D layout col=lane&15, row=quad*4+reg; scale by dis, store bf16
    #pragma unroll
    for (int r = 0; r < 4; r++) {
        int gr = row0 + wave * 16 + quad * 4 + r;
        if (gr < M) {
            float dsc = dis[gr];
            #pragma unroll
            for (int c = 0; c < 8; c++)
                h2[(size_t)gr * HID + c * 16 + lrow] = f2bf(acc[c][r] * dsc);
        }
    }
}

// ---------------------------------------------------------------------------
// Gather + fused column stats. One wave per node per iteration; the wave's
// 4 16-lane groups each take every 4th edge with a dwordx4 (8-col) load:
// one VMEM instruction fetches 4 source rows (1 KB); unroll 4 -> 16 edges
// (4 KB) in flight. No per-edge dis load (h2 pre-scaled).
// Cross-group reduce: 2 shfl_xor rounds. Stats/out from group 0.
// ---------------------------------------------------------------------------
#define GATHER_BLOCKS 2048
#define GW 4

__global__ __launch_bounds__(256) void gather_kernel(const int* __restrict__ rowptr,
                                                     const int* __restrict__ srcs,
                                                     const float* __restrict__ dis,
                                                     const uint* __restrict__ h2,   // 64 uints/row
                                                     float* __restrict__ out,
                                                     float* colsum, float* colsumsq) {
    const int wave = threadIdx.x >> 6, lane = threadIdx.x & 63;
    const int g = lane >> 4, l16 = lane & 15;
    float s[8], q[8];
    #pragma unroll
    for (int j = 0; j < 8; j++) { s[j] = 0.f; q[j] = 0.f; }

    for (int node = blockIdx.x * GW + wave; node < N_NODES; node += GATHER_BLOCKS * GW) {
        int beg = rowptr[node], end = rowptr[node + 1];
        float dn = dis[node];
        float acc[8];
        #pragma unroll
        for (int j = 0; j < 8; j++) acc[j] = 0.f;

        for (int base = beg; base < end; base += 16) {
            int idx[4];
            uint4 row[4];
            #pragma unroll
            for (int u = 0; u < 4; u++) {
                int e = base + g + 4 * u;
                idx[u] = (e < end) ? srcs[e] : -1;   // 16 ints = 1 cache line
            }
            #pragma unroll
            for (int u = 0; u < 4; u++) {
                int si = (idx[u] >= 0) ? idx[u] : 0;
                row[u] = *(const uint4*)(h2 + (size_t)si * 64 + l16 * 4);
            }
            #pragma unroll
            for (int u = 0; u < 4; u++) {
                if (idx[u] >= 0) {
                    acc[0] += bflo(row[u].x); acc[1] += bfhi(row[u].x);
                    acc[2] += bflo(row[u].y); acc[3] += bfhi(row[u].y);
                    acc[4] += bflo(row[u].z); acc[5] += bfhi(row[u].z);
                    acc[6] += bflo(row[u].w); acc[7] += bfhi(row[u].w);
                }
            }
        }

        // reduce across the 4 lane groups (cols identical for same l16)
        #pragma unroll
        for (int j = 0; j < 8; j++) {
            acc[j] += __shfl_xor(acc[j], 16, 64);
            acc[j] += __shfl_xor(acc[j], 32, 64);
        }

        // self-loop (h2 already dis-scaled), then final dn factor
        uint4 self = *(const uint4*)(h2 + (size_t)node * 64 + l16 * 4);
        acc[0] += bflo(self.x); acc[1] += bfhi(self.x);
        acc[2] += bflo(self.y); acc[3] += bfhi(self.y);
        acc[4] += bflo(self.z); acc[5] += bfhi(self.z);
        acc[6] += bflo(self.w); acc[7] += bfhi(self.w);
        #pragma unroll
        for (int j = 0; j < 8; j++) acc[j] *= dn;

        if (g == 0) {
            float* op = out + (size_t)node * HID + l16 * 8;
            *(float4*)op       = make_float4(acc[0], acc[1], acc[2], acc[3]);
            *(float4*)(op + 4) = make_float4(acc[4], acc[5], acc[6], acc[7]);
            #pragma unroll
            for (int j = 0; j < 8; j++) {
                s[j] += acc[j];
                q[j] = fmaf(acc[j], acc[j], q[j]);
            }
        }
    }

    // block stat reduction
    __shared__ float rs[GW][HID];
    __shared__ float rq[GW][HID];
    if (g == 0) {
        #pragma unroll
        for (int j = 0; j < 8; j++) {
            rs[wave][l16 * 8 + j] = s[j];
            rq[wave][l16 * 8 + j] = q[j];
        }
    }
    __syncthreads();
    int t = threadIdx.x;
    if (t < HID) {
        float ss = rs[0][t] + rs[1][t] + rs[2][t] + rs[3][t];
        float qq = rq[0][t] + rq[1][t] + rq[2][t] + rq[3][t];
        atomicAdd(&colsum[t], ss);
        atomicAdd(&colsumsq[t], qq);
    }
}

// ---------------------------------------------------------------------------
// BN (training stats, biased var) + ReLU, in place. (bias b cancels in BN)
// ---------------------------------------------------------------------------
__global__ __launch_bounds__(256) void bn_relu_kernel(float* __restrict__ out,
                                                      const float* __restrict__ colsum,
                                                      const float* __restrict__ colsumsq,
                                                      const float* __restrict__ gamma,
                                                      const float* __restrict__ beta, int M) {
    size_t i = (size_t)blockIdx.x * 256 + threadIdx.x;
    size_t total = (size_t)M * (HID / 4);
    if (i >= total) return;
    int c4 = (int)((i & (HID / 4 - 1)) * 4);
    float4 v = ((const float4*)out)[i];
    float vv[4] = {v.x, v.y, v.z, v.w};
    float res[4];
    const float invN = 1.0f / (float)M;
    #pragma unroll
    for (int j = 0; j < 4; j++) {
        int c = c4 + j;
        float mean = colsum[c] * invN;
        float var  = colsumsq[c] * invN - mean * mean;
        var = fmaxf(var, 0.0f);
        float sc = gamma[c] * rsqrtf(var + BN_EPS);
        res[j] = fmaxf(0.0f, (vv[j] - mean) * sc + beta[c]);
    }
    ((float4*)out)[i] = make_float4(res[0], res[1], res[2], res[3]);
}

// ---------------------------------------------------------------------------
extern "C" void kernel_launch(void* const* d_in, const int* in_sizes, int n_in,
                              void* d_out, int out_size, void* d_ws, size_t ws_size,
                              hipStream_t stream) {
    const float* x     = (const float*)d_in[0];
    const int*   ei    = (const int*)  d_in[1];   // [2,E] flat: row(src) then col(dst)
    const float* W     = (const float*)d_in[2];
    // d_in[3] = b: cancels inside BatchNorm -> unused
    const float* gamma = (const float*)d_in[4];
    const float* beta  = (const float*)d_in[5];
    float* out = (float*)d_out;

    const int* row = ei;
    const int* col = ei + N_EDGES;

    // workspace layout (4-byte words)
    int*    cnt       = (int*)d_ws;                        // [50000]
    float*  dis       = (float*)d_ws + 50000;              // [50000]
    int*    rowptr    = (int*)d_ws + 100000;               // [50001]
    int*    cursor    = (int*)d_ws + 150016;               // [50000]
    int*    blocksums = (int*)d_ws + 200016;               // [256]
    int*    srcs      = (int*)d_ws + 200272;               // [600000]
    ushort* Wt        = (ushort*)((int*)d_ws + 800272);    // [128*256] bf16 (16384 words)
    ushort* h2        = (ushort*)((int*)d_ws + 816656);    // [50000*128] bf16 (3.2M words)
    float*  colsum    = (float*)d_ws + 4016656;            // [128]
    float*  colsumsq  = (float*)d_ws + 4016784;            // [128]

    zero_kernel<<<(N_NODES + 255) / 256, 256, 0, stream>>>(cnt, colsum, N_NODES);

    hist_prepw_kernel<<<HIST_BLOCKS + PREPW_BLOCKS, 256, 0, stream>>>(col, cnt, W, Wt);

    scan_blocksum_kernel<<<SCAN_BLOCKS, 256, 0, stream>>>(cnt, blocksums, N_NODES);
    scan_final_kernel<<<SCAN_BLOCKS, 256, 0, stream>>>(cnt, blocksums, rowptr, cursor, dis, N_NODES);

    fill_kernel<<<HIST_BLOCKS, 256, 0, stream>>>(row, col, cursor, srcs, N_EDGES);

    gemm_kernel<<<(N_NODES + 63) / 64, 256, 0, stream>>>(x, Wt, dis, h2, N_NODES);

    gather_kernel<<<GATHER_BLOCKS, 256, 0, stream>>>(rowptr, srcs, dis, (const uint*)h2, out,
                                                     colsum, colsumsq);

    {
        size_t total = (size_t)N_NODES * (HID / 4);
        bn_relu_kernel<<<(int)((total + 255) / 256), 256, 0, stream>>>(out, colsum, colsumsq, gamma, beta, N_NODES);
    }
}